// Round 7
// baseline (252.114 us; speedup 1.0000x reference)
//
#include <hip/hip_runtime.h>
#include <math.h>

typedef __bf16 bf16_t;
typedef bf16_t bf16x8 __attribute__((ext_vector_type(8)));
typedef bf16_t bf16x4 __attribute__((ext_vector_type(4)));
typedef short  s16x4  __attribute__((ext_vector_type(4)));
typedef float  f32x4  __attribute__((ext_vector_type(4)));

#define DIM_   1024
#define NHEADS 16
#define HDIM   64
#define SEQ    2048
#define BATCH  2

// log2(e)/8 : folded into q at RoPE time so attention softmax is exp2(s)
#define QK_SCALE 0.18033688011112042f

__device__ __forceinline__ s16x4 as_s16x4(bf16x4 v) {
    union { bf16x4 b; s16x4 s; } u; u.b = v; return u.s;
}

// async global->LDS, 16 B per lane; LDS dest = wave-uniform base + lane*16
__device__ __forceinline__ void gld16(const bf16_t* g, bf16_t* l) {
    __builtin_amdgcn_global_load_lds(
        (const __attribute__((address_space(1))) void*)g,
        (__attribute__((address_space(3))) void*)l, 16, 0, 0);
}

// ---------------------------------------------------------------------------
// Fused fp32->bf16 cast of x, w_qkv, w_out.
// ---------------------------------------------------------------------------
#define XCNT   (4096u * 1024u)
#define WQCNT  (3072u * 1024u)
#define WOCNT  (1024u * 1024u)
__global__ __launch_bounds__(256) void cast3(const float* __restrict__ s0,
                                             const float* __restrict__ s1,
                                             const float* __restrict__ s2,
                                             bf16_t* __restrict__ d0,
                                             bf16_t* __restrict__ d1,
                                             bf16_t* __restrict__ d2) {
    size_t i = ((size_t)blockIdx.x * 256 + threadIdx.x) * 8;
    const float* s; bf16_t* d; size_t off;
    if (i < XCNT)               { s = s0; d = d0; off = i; }
    else if (i < XCNT + WQCNT)  { s = s1; d = d1; off = i - XCNT; }
    else                        { s = s2; d = d2; off = i - XCNT - WQCNT; }
    float4 a = *(const float4*)(s + off);
    float4 b = *(const float4*)(s + off + 4);
    bf16x8 o = { (bf16_t)a.x, (bf16_t)a.y, (bf16_t)a.z, (bf16_t)a.w,
                 (bf16_t)b.x, (bf16_t)b.y, (bf16_t)b.z, (bf16_t)b.w };
    *(bf16x8*)(d + off) = o;
}

// ---------------------------------------------------------------------------
// m97-style bf16 GEMM (unchanged): 128x128 tile, BK=32, global_load_lds
// width-16 staging, unpadded LDS, b128 frag reads.
// ---------------------------------------------------------------------------
template <bool QKV>
__global__ __launch_bounds__(256) void gemm_lds(const bf16_t* __restrict__ A,
                                                const bf16_t* __restrict__ B,
                                                const float* __restrict__ bias,
                                                void* __restrict__ Cout,
                                                bf16_t* __restrict__ vt,
                                                int M, int N, int K) {
    __shared__ __align__(16) bf16_t As[128 * 32];
    __shared__ __align__(16) bf16_t Bs[128 * 32];
    const int tid  = threadIdx.x;
    const int m0   = blockIdx.y * 128;
    const int n0   = blockIdx.x * 128;
    const int w    = tid >> 6;
    const int lane = tid & 63;
    const int m16  = lane & 15;
    const int quad = lane >> 4;
    const int wm   = (w >> 1) * 64;
    const int wn   = (w & 1) * 64;
    const int lrow = lane >> 2;
    const int lcol = (lane & 3) * 8;

    const bf16_t* pa0 = A + (size_t)(m0 + w * 16 + lrow) * K + lcol;
    const bf16_t* pb0 = B + (size_t)(n0 + w * 16 + lrow) * K + lcol;
    bf16_t* lA0 = &As[(w * 16) * 32];
    bf16_t* lA1 = &As[(64 + w * 16) * 32];
    bf16_t* lB0 = &Bs[(w * 16) * 32];
    bf16_t* lB1 = &Bs[(64 + w * 16) * 32];

    f32x4 acc[4][4] = {};

    for (int k0 = 0; k0 < K; k0 += 32) {
        __syncthreads();
        gld16(pa0 + k0, lA0);
        gld16(pa0 + (size_t)64 * K + k0, lA1);
        gld16(pb0 + k0, lB0);
        gld16(pb0 + (size_t)64 * K + k0, lB1);
        __syncthreads();

        bf16x8 af[4], bfr[4];
#pragma unroll
        for (int i = 0; i < 4; ++i)
            af[i] = *(const bf16x8*)(&As[(wm + i * 16 + m16) * 32 + quad * 8]);
#pragma unroll
        for (int j = 0; j < 4; ++j)
            bfr[j] = *(const bf16x8*)(&Bs[(wn + j * 16 + m16) * 32 + quad * 8]);
#pragma unroll
        for (int i = 0; i < 4; ++i)
#pragma unroll
            for (int j = 0; j < 4; ++j)
                acc[i][j] = __builtin_amdgcn_mfma_f32_16x16x32_bf16(af[i], bfr[j], acc[i][j], 0, 0, 0);
    }

    if (QKV && n0 >= 2 * DIM_) {
        const int b      = m0 >> 11;
        const int s_base = (m0 & (SEQ - 1)) + wm;
#pragma unroll
        for (int j = 0; j < 4; ++j) {
            const int cit = wn + j * 16 + m16;
            const int h   = ((n0 - 2 * DIM_) >> 6) + (cit >> 6);
            const int d   = cit & 63;
            bf16_t* vrow = vt + ((size_t)(b * 16 + h) * 64 + d) * SEQ + s_base;
#pragma unroll
            for (int i = 0; i < 4; ++i) {
                bf16x4 ov = { (bf16_t)acc[i][j][0], (bf16_t)acc[i][j][1],
                              (bf16_t)acc[i][j][2], (bf16_t)acc[i][j][3] };
                *(bf16x4*)(vrow + i * 16 + quad * 4) = ov;
            }
        }
    } else if (QKV) {
        bf16_t* C = (bf16_t*)Cout;
#pragma unroll
        for (int i = 0; i < 4; ++i)
#pragma unroll
            for (int j = 0; j < 4; ++j) {
                const int col = n0 + wn + j * 16 + m16;
#pragma unroll
                for (int r = 0; r < 4; ++r)
                    C[(size_t)(m0 + wm + i * 16 + quad * 4 + r) * N + col] = (bf16_t)acc[i][j][r];
            }
    } else {
        float* C = (float*)Cout;
#pragma unroll
        for (int j = 0; j < 4; ++j) {
            const int col = n0 + wn + j * 16 + m16;
            const float bv = bias[col];
#pragma unroll
            for (int i = 0; i < 4; ++i)
#pragma unroll
                for (int r = 0; r < 4; ++r)
                    C[(size_t)(m0 + wm + i * 16 + quad * 4 + r) * N + col] = acc[i][j][r] + bv;
        }
    }
}

// ---------------------------------------------------------------------------
// RoPE in place on bf16 qkv (q and k thirds). q scaled by QK_SCALE.
// ---------------------------------------------------------------------------
__global__ __launch_bounds__(256) void rope_bf16(bf16_t* __restrict__ qkv) {
    __shared__ float ctab[8][32];
    __shared__ float stab[8][32];
    const int tid = threadIdx.x;
    const int sl  = tid >> 5, j = tid & 31;
    const int s   = (int)((blockIdx.x * 8 + sl) & (SEQ - 1));
    const float freq = exp2f(-0.41524101186092029f * (float)j);  // 10000^(-j/32)
    float sn, cs;
    sincosf((float)s * freq, &sn, &cs);
    ctab[sl][j] = cs;
    stab[sl][j] = sn;
    __syncthreads();

    const int gid   = blockIdx.x * 256 + tid;
    const int m     = gid >> 5;
    const int rr    = gid & 31;
    const int which = rr >> 4;
    const int hh    = rr & 15;
    const float osc = (which == 0) ? QK_SCALE : 1.0f;

    bf16_t* p = qkv + (size_t)m * (3 * DIM_) + which * DIM_ + hh * HDIM;
    union { bf16_t e[64]; bf16x8 v[8]; } X, O;
#pragma unroll
    for (int i = 0; i < 8; ++i) X.v[i] = *(const bf16x8*)(p + i * 8);
#pragma unroll
    for (int t = 0; t < 32; ++t) {
        const float x1 = (float)X.e[2 * t];
        const float x2 = (float)X.e[2 * t + 1];
        const float c  = ctab[sl][t];
        const float s2 = stab[sl][t];
        O.e[t]      = (bf16_t)((x1 * c - x2 * s2) * osc);
        O.e[32 + t] = (bf16_t)((x1 * s2 + x2 * c) * osc);
    }
#pragma unroll
    for (int i = 0; i < 8; ++i) *(bf16x8*)(p + i * 8) = O.v[i];
}

// ---------------------------------------------------------------------------
// Flash attention, key-split waves, WAVE-PRIVATE double-buffered LDS staging,
// NO barriers in the main loop. Grid (SEQ/64, B*H), 256 thr = 4 waves.
// Wave w owns keys w*16..+15 of every 64-key tile for all 64 queries:
//   - K slice (16 rows x 64d) and V^T slice (64d x 16 keys) both partition
//     by key -> each wave stages ITS OWN slice into ITS OWN LDS region with
//     coalesced b128 loads; no cross-wave sharing until the epilogue.
//   - double-buffer: issue tile t+1 loads -> compute tile t -> write prefetch
//     to alt buffer; vmcnt wait lands after compute.
//   - epilogue Ored/Lred LDS aliases the staging buffers (barrier first).
// ---------------------------------------------------------------------------
__global__ __launch_bounds__(256) void attn_mfma(const bf16_t* __restrict__ qkv,
                                                 const bf16_t* __restrict__ vt,
                                                 bf16_t* __restrict__ out) {
    __shared__ __align__(16) char smem[39936];
    bf16_t* KW   = (bf16_t*)smem;                 // [w][buf][16*72]  18432 B
    bf16_t* VW   = (bf16_t*)(smem + 18432);       // [w][buf][64*20]  20480 B
    float*  Ored = (float*)smem;                  // 16640 B (epilogue alias)
    float*  Lred = (float*)(smem + 16640);        //  1024 B

    const int tid  = threadIdx.x;
    const int w    = tid >> 6;
    const int lane = tid & 63;
    const int m16  = lane & 15;
    const int quad = lane >> 4;
    const int bh   = blockIdx.y;
    const int b    = bh >> 4;
    const int hh   = bh & 15;
    const int q0   = blockIdx.x * 64;

    const size_t rs = 3 * DIM_;
    const bf16_t* qbase = qkv + (size_t)(b * SEQ) * rs + hh * HDIM;
    const bf16_t* vtg   = vt + (size_t)bh * 64 * SEQ;

    // wave-private staging pointers
    const int krow = lane >> 2;             // 0..15
    const int kcol = (lane & 3) << 4;       // 0,16,32,48
    const bf16_t* kg = qbase + DIM_ + (size_t)(w * 16 + krow) * rs + kcol;
    const bf16_t* vg = vtg + (size_t)lane * SEQ + w * 16;
    bf16_t* kl[2] = { &KW[(w * 2 + 0) * 1152 + krow * 72 + kcol],
                      &KW[(w * 2 + 1) * 1152 + krow * 72 + kcol] };
    bf16_t* vl[2] = { &VW[(w * 2 + 0) * 1280 + lane * 20],
                      &VW[(w * 2 + 1) * 1280 + lane * 20] };
    const bf16_t* kf[2] = { &KW[(w * 2 + 0) * 1152 + m16 * 72 + quad * 8],
                            &KW[(w * 2 + 1) * 1152 + m16 * 72 + quad * 8] };
    const bf16_t* vf[2] = { &VW[(w * 2 + 0) * 1280 + m16 * 20 + quad * 4],
                            &VW[(w * 2 + 1) * 1280 + m16 * 20 + quad * 4] };

    // Q fragments: qf[n][kt] = Q[q0+n*16+m16][kt*32+quad*8 ..+7]
    bf16x8 qf[4][2];
#pragma unroll
    for (int n = 0; n < 4; ++n)
#pragma unroll
        for (int kt = 0; kt < 2; ++kt)
            qf[n][kt] = *(const bf16x8*)(qbase + (size_t)(q0 + n * 16 + m16) * rs + kt * 32 + quad * 8);

    f32x4 o[4][4] = {};  // o[ds][n]: partial O^T over this wave's keys
    float lp[4] = {};    // per-lane partial l for q = n*16+m16

    // preload tile 0 into buf0
    bf16x8 kr0 = *(const bf16x8*)(kg);
    bf16x8 kr1 = *(const bf16x8*)(kg + 8);
    bf16x8 vr0 = *(const bf16x8*)(vg);
    bf16x8 vr1 = *(const bf16x8*)(vg + 8);
    *(bf16x8*)(kl[0])     = kr0;
    *(bf16x8*)(kl[0] + 8) = kr1;
    *(bf16x8*)(vl[0])     = vr0;
    *(bf16x8*)(vl[0] + 8) = vr1;

    auto compute_tile = [&](int buf) {
        bf16x8 ak0 = *(const bf16x8*)(kf[buf]);
        bf16x8 ak1 = *(const bf16x8*)(kf[buf] + 32);
        bf16x4 va[4];
#pragma unroll
        for (int ds = 0; ds < 4; ++ds)
            va[ds] = *(const bf16x4*)(vf[buf] + ds * 16 * 20);
        s16x4 pb[4];
#pragma unroll
        for (int n = 0; n < 4; ++n) {
            f32x4 c = {};
            c = __builtin_amdgcn_mfma_f32_16x16x32_bf16(ak0, qf[n][0], c, 0, 0, 0);
            c = __builtin_amdgcn_mfma_f32_16x16x32_bf16(ak1, qf[n][1], c, 0, 0, 0);
            bf16x4 pv;
#pragma unroll
            for (int r = 0; r < 4; ++r) {
                const float p = __builtin_amdgcn_exp2f(c[r]);
                lp[n] += p;
                pv[r] = (bf16_t)p;
            }
            pb[n] = as_s16x4(pv);
        }
#pragma unroll
        for (int ds = 0; ds < 4; ++ds)
#pragma unroll
            for (int n = 0; n < 4; ++n)
                o[ds][n] = __builtin_amdgcn_mfma_f32_16x16x16bf16_1k(as_s16x4(va[ds]), pb[n], o[ds][n], 0, 0, 0);
    };

    for (int t = 0; t < 31; ++t) {
        // issue next-tile global loads (vmcnt consumed at the writes below)
        kg += (size_t)64 * rs;
        vg += 64;
        kr0 = *(const bf16x8*)(kg);
        kr1 = *(const bf16x8*)(kg + 8);
        vr0 = *(const bf16x8*)(vg);
        vr1 = *(const bf16x8*)(vg + 8);

        compute_tile(t & 1);

        const int nb = (t + 1) & 1;
        *(bf16x8*)(kl[nb])     = kr0;
        *(bf16x8*)(kl[nb] + 8) = kr1;
        *(bf16x8*)(vl[nb])     = vr0;
        *(bf16x8*)(vl[nb] + 8) = vr1;
    }
    compute_tile(1);   // tile 31 is in buf 1

    // ---- l reduction: over quads (shfl), then over waves (LDS) ----
#pragma unroll
    for (int n = 0; n < 4; ++n) {
        lp[n] += __shfl_xor(lp[n], 16);
        lp[n] += __shfl_xor(lp[n], 32);
    }
    __syncthreads();   // all waves done with staging LDS before aliasing
    if (quad == 0) {
#pragma unroll
        for (int n = 0; n < 4; ++n) Lred[w * 64 + n * 16 + m16] = lp[n];
    }
    __syncthreads();
    const float linv = 1.0f / (Lred[lane] + Lred[64 + lane] + Lred[128 + lane] + Lred[192 + lane]);

    // ---- O reduction: 4 phases; wave p owns dim-quarter p ----
    const size_t obase = (size_t)(b * SEQ + q0 + lane) * DIM_ + hh * HDIM;
#pragma unroll
    for (int p = 0; p < 4; ++p) {
        __syncthreads();
#pragma unroll
        for (int n = 0; n < 4; ++n)
#pragma unroll
            for (int r = 0; r < 4; ++r)
                Ored[w * 1040 + (quad * 4 + r) * 65 + n * 16 + m16] = o[p][n][r];
        __syncthreads();
        if (w == p) {
            union { bf16_t e[16]; bf16x8 v[2]; } ob;
#pragma unroll
            for (int d = 0; d < 16; ++d) {
                const float v = Ored[d * 65 + lane] + Ored[1040 + d * 65 + lane] +
                                Ored[2080 + d * 65 + lane] + Ored[3120 + d * 65 + lane];
                ob.e[d] = (bf16_t)(v * linv);
            }
            *(bf16x8*)(out + obase + p * 16)     = ob.v[0];
            *(bf16x8*)(out + obase + p * 16 + 8) = ob.v[1];
        }
    }
}

// ---------------------------------------------------------------------------
extern "C" void kernel_launch(void* const* d_in, const int* in_sizes, int n_in,
                              void* d_out, int out_size, void* d_ws, size_t ws_size,
                              hipStream_t stream) {
    const float* x     = (const float*)d_in[0];
    const float* w_qkv = (const float*)d_in[1];
    const float* w_out = (const float*)d_in[2];
    const float* b_out = (const float*)d_in[3];
    float* out = (float*)d_out;

    const int M = BATCH * SEQ;  // 4096

    bf16_t* qkv_b  = (bf16_t*)d_ws;                            // 4096x3072
    bf16_t* attn_b = qkv_b + (size_t)M * 3 * DIM_;             // 4096x1024
    bf16_t* vt_b   = attn_b + (size_t)M * DIM_;                // 32 heads x 64 x SEQ
    bf16_t* xb     = vt_b + (size_t)BATCH * NHEADS * HDIM * SEQ;
    bf16_t* wqkvb  = xb + (size_t)M * DIM_;
    bf16_t* woutb  = wqkvb + (size_t)3 * DIM_ * DIM_;

    // 0) cast x, w_qkv, w_out to bf16
    cast3<<<(XCNT + WQCNT + WOCNT) / (256 * 8), 256, 0, stream>>>(
        x, w_qkv, w_out, xb, wqkvb, woutb);

    // 1) qkv = x @ w_qkv^T  (q,k -> qkv_b; v -> vt_b transposed)
    gemm_lds<true><<<dim3(3 * DIM_ / 128, M / 128), 256, 0, stream>>>(
        xb, wqkvb, nullptr, qkv_b, vt_b, M, 3 * DIM_, DIM_);

    // 2) RoPE in place on q,k
    rope_bf16<<<(M * 2 * NHEADS) / 256, 256, 0, stream>>>(qkv_b);

    // 3) flash attention -> attn_b
    attn_mfma<<<dim3(SEQ / 64, BATCH * NHEADS), 256, 0, stream>>>(qkv_b, vt_b, attn_b);

    // 4) out = attn @ w_out^T + b_out (fp32)
    gemm_lds<false><<<dim3(DIM_ / 128, M / 128), 256, 0, stream>>>(
        attn_b, woutb, b_out, out, nullptr, M, DIM_, DIM_);
}

// Round 8
// 225.163 us; speedup vs baseline: 1.1197x; 1.1197x over previous
//
#include <hip/hip_runtime.h>
#include <math.h>

typedef __bf16 bf16_t;
typedef bf16_t bf16x8 __attribute__((ext_vector_type(8)));
typedef bf16_t bf16x4 __attribute__((ext_vector_type(4)));
typedef short  s16x4  __attribute__((ext_vector_type(4)));
typedef float  f32x4  __attribute__((ext_vector_type(4)));

#define DIM_   1024
#define NHEADS 16
#define HDIM   64
#define SEQ    2048
#define BATCH  2

// log2(e)/8 : folded into q at RoPE time so attention softmax is exp2(s)
#define QK_SCALE 0.18033688011112042f

__device__ __forceinline__ s16x4 as_s16x4(bf16x4 v) {
    union { bf16x4 b; s16x4 s; } u; u.b = v; return u.s;
}

// async global->LDS, 16 B per lane; LDS dest = wave-uniform base + lane*16
__device__ __forceinline__ void gld16(const bf16_t* g, bf16_t* l) {
    __builtin_amdgcn_global_load_lds(
        (const __attribute__((address_space(1))) void*)g,
        (__attribute__((address_space(3))) void*)l, 16, 0, 0);
}

// ---------------------------------------------------------------------------
// Fused fp32->bf16 cast of x, w_qkv, w_out.
// ---------------------------------------------------------------------------
#define XCNT   (4096u * 1024u)
#define WQCNT  (3072u * 1024u)
#define WOCNT  (1024u * 1024u)
__global__ __launch_bounds__(256) void cast3(const float* __restrict__ s0,
                                             const float* __restrict__ s1,
                                             const float* __restrict__ s2,
                                             bf16_t* __restrict__ d0,
                                             bf16_t* __restrict__ d1,
                                             bf16_t* __restrict__ d2) {
    size_t i = ((size_t)blockIdx.x * 256 + threadIdx.x) * 8;
    const float* s; bf16_t* d; size_t off;
    if (i < XCNT)               { s = s0; d = d0; off = i; }
    else if (i < XCNT + WQCNT)  { s = s1; d = d1; off = i - XCNT; }
    else                        { s = s2; d = d2; off = i - XCNT - WQCNT; }
    float4 a = *(const float4*)(s + off);
    float4 b = *(const float4*)(s + off + 4);
    bf16x8 o = { (bf16_t)a.x, (bf16_t)a.y, (bf16_t)a.z, (bf16_t)a.w,
                 (bf16_t)b.x, (bf16_t)b.y, (bf16_t)b.z, (bf16_t)b.w };
    *(bf16x8*)(d + off) = o;
}

// ---------------------------------------------------------------------------
// m97-style bf16 GEMM (unchanged): 128x128 tile, BK=32, global_load_lds
// width-16 staging, unpadded LDS, b128 frag reads.
// ---------------------------------------------------------------------------
template <bool QKV>
__global__ __launch_bounds__(256) void gemm_lds(const bf16_t* __restrict__ A,
                                                const bf16_t* __restrict__ B,
                                                const float* __restrict__ bias,
                                                void* __restrict__ Cout,
                                                bf16_t* __restrict__ vt,
                                                int M, int N, int K) {
    __shared__ __align__(16) bf16_t As[128 * 32];
    __shared__ __align__(16) bf16_t Bs[128 * 32];
    const int tid  = threadIdx.x;
    const int m0   = blockIdx.y * 128;
    const int n0   = blockIdx.x * 128;
    const int w    = tid >> 6;
    const int lane = tid & 63;
    const int m16  = lane & 15;
    const int quad = lane >> 4;
    const int wm   = (w >> 1) * 64;
    const int wn   = (w & 1) * 64;
    const int lrow = lane >> 2;
    const int lcol = (lane & 3) * 8;

    const bf16_t* pa0 = A + (size_t)(m0 + w * 16 + lrow) * K + lcol;
    const bf16_t* pb0 = B + (size_t)(n0 + w * 16 + lrow) * K + lcol;
    bf16_t* lA0 = &As[(w * 16) * 32];
    bf16_t* lA1 = &As[(64 + w * 16) * 32];
    bf16_t* lB0 = &Bs[(w * 16) * 32];
    bf16_t* lB1 = &Bs[(64 + w * 16) * 32];

    f32x4 acc[4][4] = {};

    for (int k0 = 0; k0 < K; k0 += 32) {
        __syncthreads();
        gld16(pa0 + k0, lA0);
        gld16(pa0 + (size_t)64 * K + k0, lA1);
        gld16(pb0 + k0, lB0);
        gld16(pb0 + (size_t)64 * K + k0, lB1);
        __syncthreads();

        bf16x8 af[4], bfr[4];
#pragma unroll
        for (int i = 0; i < 4; ++i)
            af[i] = *(const bf16x8*)(&As[(wm + i * 16 + m16) * 32 + quad * 8]);
#pragma unroll
        for (int j = 0; j < 4; ++j)
            bfr[j] = *(const bf16x8*)(&Bs[(wn + j * 16 + m16) * 32 + quad * 8]);
#pragma unroll
        for (int i = 0; i < 4; ++i)
#pragma unroll
            for (int j = 0; j < 4; ++j)
                acc[i][j] = __builtin_amdgcn_mfma_f32_16x16x32_bf16(af[i], bfr[j], acc[i][j], 0, 0, 0);
    }

    if (QKV && n0 >= 2 * DIM_) {
        const int b      = m0 >> 11;
        const int s_base = (m0 & (SEQ - 1)) + wm;
#pragma unroll
        for (int j = 0; j < 4; ++j) {
            const int cit = wn + j * 16 + m16;
            const int h   = ((n0 - 2 * DIM_) >> 6) + (cit >> 6);
            const int d   = cit & 63;
            bf16_t* vrow = vt + ((size_t)(b * 16 + h) * 64 + d) * SEQ + s_base;
#pragma unroll
            for (int i = 0; i < 4; ++i) {
                bf16x4 ov = { (bf16_t)acc[i][j][0], (bf16_t)acc[i][j][1],
                              (bf16_t)acc[i][j][2], (bf16_t)acc[i][j][3] };
                *(bf16x4*)(vrow + i * 16 + quad * 4) = ov;
            }
        }
    } else if (QKV) {
        bf16_t* C = (bf16_t*)Cout;
#pragma unroll
        for (int i = 0; i < 4; ++i)
#pragma unroll
            for (int j = 0; j < 4; ++j) {
                const int col = n0 + wn + j * 16 + m16;
#pragma unroll
                for (int r = 0; r < 4; ++r)
                    C[(size_t)(m0 + wm + i * 16 + quad * 4 + r) * N + col] = (bf16_t)acc[i][j][r];
            }
    } else {
        float* C = (float*)Cout;
#pragma unroll
        for (int j = 0; j < 4; ++j) {
            const int col = n0 + wn + j * 16 + m16;
            const float bv = bias[col];
#pragma unroll
            for (int i = 0; i < 4; ++i)
#pragma unroll
                for (int r = 0; r < 4; ++r)
                    C[(size_t)(m0 + wm + i * 16 + quad * 4 + r) * N + col] = acc[i][j][r] + bv;
        }
    }
}

// ---------------------------------------------------------------------------
// RoPE in place on bf16 qkv (q and k thirds). q scaled by QK_SCALE.
// ---------------------------------------------------------------------------
__global__ __launch_bounds__(256) void rope_bf16(bf16_t* __restrict__ qkv) {
    __shared__ float ctab[8][32];
    __shared__ float stab[8][32];
    const int tid = threadIdx.x;
    const int sl  = tid >> 5, j = tid & 31;
    const int s   = (int)((blockIdx.x * 8 + sl) & (SEQ - 1));
    const float freq = exp2f(-0.41524101186092029f * (float)j);  // 10000^(-j/32)
    float sn, cs;
    sincosf((float)s * freq, &sn, &cs);
    ctab[sl][j] = cs;
    stab[sl][j] = sn;
    __syncthreads();

    const int gid   = blockIdx.x * 256 + tid;
    const int m     = gid >> 5;
    const int rr    = gid & 31;
    const int which = rr >> 4;
    const int hh    = rr & 15;
    const float osc = (which == 0) ? QK_SCALE : 1.0f;

    bf16_t* p = qkv + (size_t)m * (3 * DIM_) + which * DIM_ + hh * HDIM;
    union { bf16_t e[64]; bf16x8 v[8]; } X, O;
#pragma unroll
    for (int i = 0; i < 8; ++i) X.v[i] = *(const bf16x8*)(p + i * 8);
#pragma unroll
    for (int t = 0; t < 32; ++t) {
        const float x1 = (float)X.e[2 * t];
        const float x2 = (float)X.e[2 * t + 1];
        const float c  = ctab[sl][t];
        const float s2 = stab[sl][t];
        O.e[t]      = (bf16_t)((x1 * c - x2 * s2) * osc);
        O.e[32 + t] = (bf16_t)((x1 * s2 + x2 * c) * osc);
    }
#pragma unroll
    for (int i = 0; i < 8; ++i) *(bf16x8*)(p + i * 8) = O.v[i];
}

// ---------------------------------------------------------------------------
// Flash attention, key-split waves (R5 structure) + REGISTER DOUBLE-BUFFERED
// staging. Grid (SEQ/64, B*H), 256 thr = 4 waves; wave w owns keys w*16..+15.
// Per tile: sync -> ds_write staged regs -> sync -> issue next-tile global
// loads into regs -> compute. Loads overlap the whole compute phase; the
// vmcnt wait lands at the NEXT iteration's ds_write (post-compute), so
// exposed memory latency ~ 0. Staging stays fully coalesced (R5 pattern).
// ---------------------------------------------------------------------------
__global__ __launch_bounds__(256) void attn_mfma(const bf16_t* __restrict__ qkv,
                                                 const bf16_t* __restrict__ vt,
                                                 bf16_t* __restrict__ out) {
    __shared__ __align__(16) char smem[18432];
    bf16_t* Ks   = (bf16_t*)smem;             // 64 x 72 bf16 (9216 B)
    bf16_t* Vt   = (bf16_t*)(smem + 9216);    // 64 x 72 bf16 (9216 B)
    float*  Ored = (float*)smem;              // epilogue alias: 16640 B
    float*  Lred = (float*)(smem + 16640);    // 1024 B

    const int tid  = threadIdx.x;
    const int w    = tid >> 6;
    const int lane = tid & 63;
    const int m16  = lane & 15;
    const int quad = lane >> 4;
    const int bh   = blockIdx.y;
    const int b    = bh >> 4;
    const int hh   = bh & 15;
    const int q0   = blockIdx.x * 64;

    const size_t rs = 3 * DIM_;
    const bf16_t* qbase = qkv + (size_t)(b * SEQ) * rs + hh * HDIM;
    const bf16_t* kbase = qbase + DIM_;
    const bf16_t* vtg   = vt + (size_t)bh * 64 * SEQ;

    // Q fragments: qf[n][kt] = Q[q0+n*16+m16][kt*32+quad*8 ..+7]
    bf16x8 qf[4][2];
#pragma unroll
    for (int n = 0; n < 4; ++n)
#pragma unroll
        for (int kt = 0; kt < 2; ++kt)
            qf[n][kt] = *(const bf16x8*)(qbase + (size_t)(q0 + n * 16 + m16) * rs + kt * 32 + quad * 8);

    f32x4 o[4][4] = {};  // o[ds][n]: partial O^T over this wave's keys
    float lp[4] = {};    // per-lane partial l for q = n*16+m16

    // coalesced staging geometry (R5 pattern): 256 threads cover 32 rows/pass
    const int srow = tid >> 3;          // 0..31
    const int sc8  = (tid & 7) * 8;     // 0..56

    // staged registers: tile t's K rows (srow, srow+32) and V^T rows
    bf16x8 kreg[2], vreg[2];
#pragma unroll
    for (int p = 0; p < 2; ++p) {
        const int row = srow + p * 32;
        kreg[p] = *(const bf16x8*)(kbase + (size_t)row * rs + sc8);
        vreg[p] = *(const bf16x8*)(vtg + (size_t)row * SEQ + sc8);
    }

    for (int t = 0; t < 32; ++t) {
        __syncthreads();   // previous tile's compute done; LDS reusable
#pragma unroll
        for (int p = 0; p < 2; ++p) {
            const int row = srow + p * 32;
            *(bf16x8*)(&Ks[row * 72 + sc8]) = kreg[p];
            *(bf16x8*)(&Vt[row * 72 + sc8]) = vreg[p];
        }
        __syncthreads();   // staged tile visible to all waves

        // issue next tile's global loads; they overlap the compute below
        if (t < 31) {
            const size_t k0n = (size_t)(t + 1) * 64;
#pragma unroll
            for (int p = 0; p < 2; ++p) {
                const int row = srow + p * 32;
                kreg[p] = *(const bf16x8*)(kbase + (k0n + row) * rs + sc8);
                vreg[p] = *(const bf16x8*)(vtg + (size_t)row * SEQ + k0n + sc8);
            }
        }

        // ---- compute tile t (R5 arithmetic, unchanged) ----
        bf16x8 ak0 = *(const bf16x8*)(&Ks[(w * 16 + m16) * 72 + 0 * 32 + quad * 8]);
        bf16x8 ak1 = *(const bf16x8*)(&Ks[(w * 16 + m16) * 72 + 1 * 32 + quad * 8]);
        bf16x4 va[4];
#pragma unroll
        for (int ds = 0; ds < 4; ++ds)
            va[ds] = *(const bf16x4*)(&Vt[(ds * 16 + m16) * 72 + w * 16 + quad * 4]);

        s16x4 pb[4];
#pragma unroll
        for (int n = 0; n < 4; ++n) {
            f32x4 c = {};
            c = __builtin_amdgcn_mfma_f32_16x16x32_bf16(ak0, qf[n][0], c, 0, 0, 0);
            c = __builtin_amdgcn_mfma_f32_16x16x32_bf16(ak1, qf[n][1], c, 0, 0, 0);
            bf16x4 pv;
#pragma unroll
            for (int r = 0; r < 4; ++r) {
                const float p = __builtin_amdgcn_exp2f(c[r]);
                lp[n] += p;
                pv[r] = (bf16_t)p;
            }
            pb[n] = as_s16x4(pv);
        }

#pragma unroll
        for (int ds = 0; ds < 4; ++ds)
#pragma unroll
            for (int n = 0; n < 4; ++n)
                o[ds][n] = __builtin_amdgcn_mfma_f32_16x16x16bf16_1k(as_s16x4(va[ds]), pb[n], o[ds][n], 0, 0, 0);
    }

    // ---- l reduction: over quads (shfl), then over waves (LDS) ----
#pragma unroll
    for (int n = 0; n < 4; ++n) {
        lp[n] += __shfl_xor(lp[n], 16);
        lp[n] += __shfl_xor(lp[n], 32);
    }
    __syncthreads();   // all waves done with staging LDS before aliasing
    if (quad == 0) {
#pragma unroll
        for (int n = 0; n < 4; ++n) Lred[w * 64 + n * 16 + m16] = lp[n];
    }
    __syncthreads();
    const float linv = 1.0f / (Lred[lane] + Lred[64 + lane] + Lred[128 + lane] + Lred[192 + lane]);

    // ---- O reduction: 4 phases; wave p owns dim-quarter p ----
    const size_t obase = (size_t)(b * SEQ + q0 + lane) * DIM_ + hh * HDIM;
#pragma unroll
    for (int p = 0; p < 4; ++p) {
        __syncthreads();
#pragma unroll
        for (int n = 0; n < 4; ++n)
#pragma unroll
            for (int r = 0; r < 4; ++r)
                Ored[w * 1040 + (quad * 4 + r) * 65 + n * 16 + m16] = o[p][n][r];
        __syncthreads();
        if (w == p) {
            union { bf16_t e[16]; bf16x8 v[2]; } ob;
#pragma unroll
            for (int d = 0; d < 16; ++d) {
                const float v = Ored[d * 65 + lane] + Ored[1040 + d * 65 + lane] +
                                Ored[2080 + d * 65 + lane] + Ored[3120 + d * 65 + lane];
                ob.e[d] = (bf16_t)(v * linv);
            }
            *(bf16x8*)(out + obase + p * 16)     = ob.v[0];
            *(bf16x8*)(out + obase + p * 16 + 8) = ob.v[1];
        }
    }
}

// ---------------------------------------------------------------------------
extern "C" void kernel_launch(void* const* d_in, const int* in_sizes, int n_in,
                              void* d_out, int out_size, void* d_ws, size_t ws_size,
                              hipStream_t stream) {
    const float* x     = (const float*)d_in[0];
    const float* w_qkv = (const float*)d_in[1];
    const float* w_out = (const float*)d_in[2];
    const float* b_out = (const float*)d_in[3];
    float* out = (float*)d_out;

    const int M = BATCH * SEQ;  // 4096

    bf16_t* qkv_b  = (bf16_t*)d_ws;                            // 4096x3072
    bf16_t* attn_b = qkv_b + (size_t)M * 3 * DIM_;             // 4096x1024
    bf16_t* vt_b   = attn_b + (size_t)M * DIM_;                // 32 heads x 64 x SEQ
    bf16_t* xb     = vt_b + (size_t)BATCH * NHEADS * HDIM * SEQ;
    bf16_t* wqkvb  = xb + (size_t)M * DIM_;
    bf16_t* woutb  = wqkvb + (size_t)3 * DIM_ * DIM_;

    // 0) cast x, w_qkv, w_out to bf16
    cast3<<<(XCNT + WQCNT + WOCNT) / (256 * 8), 256, 0, stream>>>(
        x, w_qkv, w_out, xb, wqkvb, woutb);

    // 1) qkv = x @ w_qkv^T  (q,k -> qkv_b; v -> vt_b transposed)
    gemm_lds<true><<<dim3(3 * DIM_ / 128, M / 128), 256, 0, stream>>>(
        xb, wqkvb, nullptr, qkv_b, vt_b, M, 3 * DIM_, DIM_);

    // 2) RoPE in place on q,k
    rope_bf16<<<(M * 2 * NHEADS) / 256, 256, 0, stream>>>(qkv_b);

    // 3) flash attention -> attn_b
    attn_mfma<<<dim3(SEQ / 64, BATCH * NHEADS), 256, 0, stream>>>(qkv_b, vt_b, attn_b);

    // 4) out = attn @ w_out^T + b_out (fp32)
    gemm_lds<false><<<dim3(DIM_ / 128, M / 128), 256, 0, stream>>>(
        attn_b, woutb, b_out, out, nullptr, M, DIM_, DIM_);
}